// Round 3
// baseline (407.562 us; speedup 1.0000x reference)
//
#include <hip/hip_runtime.h>
#include <hip/hip_fp16.h>

typedef _Float16 f16;
typedef __attribute__((ext_vector_type(8))) _Float16 f16x8;
typedef __attribute__((ext_vector_type(4))) _Float16 f16x4;
typedef __attribute__((ext_vector_type(2))) __fp16 fp16x2;   // cvt_pkrtz return type
typedef __attribute__((ext_vector_type(4))) float f32x4;

// ---------------------------------------------------------------------------
// Pre-pass: h (fp32) -> f16 copy in workspace (halves gather bytes).
// ---------------------------------------------------------------------------
__global__ void cvt_h_f16(const float* __restrict__ h, f16* __restrict__ hf, int n4) {
    int stride = gridDim.x * blockDim.x;
    for (int i = blockIdx.x * blockDim.x + threadIdx.x; i < n4; i += stride) {
        float4 v = reinterpret_cast<const float4*>(h)[i];
        f16x4 o = { (f16)v.x, (f16)v.y, (f16)v.z, (f16)v.w };
        reinterpret_cast<f16x4*>(hf)[i] = o;
    }
}

// ---------------------------------------------------------------------------
// Fused edge-MLP, swapped-operand MFMA (A = weights, B = data).
//   Block: 64 edges, 4 waves. Wave w owns feature rows [32w, 32w+32).
//   GEMM1: x1 = W1 (A, regs) x he^T (B, LDS)  -> lane(g,c): x1[32w+16nt+4g+r][edge 16et+c]
//   x1 exchange: cvt_pkrtz pairs -> ONE ds_write_b64 per (et,nt), natural n-order,
//                16B-chunk XOR swizzle -> GEMM2 B-frags are clean b128 reads.
//   GEMM2: x2 = W2 (A, regs) x x1^T (B, LDS)
//   Layer3: per-lane fp32 partials + shfl_xor(16,32) + tiny sbuf cross-wave sum.
// Pipeline (T14): registers R hold tile t+1's gathered rows during tile t's
// compute; ds_write after barrier B1; gathers for t+2 issued before GEMM2;
// idx prefetched 3 tiles ahead. 2 barriers/tile; sbuf double-buffered.
// ---------------------------------------------------------------------------
template<int USEF16>
__global__ __launch_bounds__(256, 2)
void mlp_edges(const float* __restrict__ h32, const f16* __restrict__ hf,
               const int* __restrict__ srcI, const int* __restrict__ dstI,
               const float* __restrict__ W1, const float* __restrict__ b1,
               const float* __restrict__ W2, const float* __restrict__ b2,
               const float* __restrict__ W3, const float* __restrict__ b3,
               float* __restrict__ out, int E, int ntiles)
{
    __shared__ f16 heS[64 * 256];      // 32 KB: [edge][k=256 f16], 16B-chunk swizzled
    __shared__ f16 x1S[64 * 128];      // 16 KB: [edge][n=128 f16], swizzled
    __shared__ float sbuf[2][4][64];   // 2 KB, parity double-buffered

    const int tid = threadIdx.x;
    const int w = tid >> 6, l = tid & 63, g = l >> 4, c = l & 15;
    const int grid = gridDim.x;

    // ---------------- weight fragments (registers, once) ----------------
    f16x8 w1f[8][2], w2f[4][2];
    f32x4 b1v[2], b2v[2], w3v[2];
    #pragma unroll
    for (int nt = 0; nt < 2; ++nt) {
        const int n = w * 32 + nt * 16 + c;
        #pragma unroll
        for (int ks = 0; ks < 8; ++ks) {
            const float4* p = reinterpret_cast<const float4*>(W1 + n * 256 + ks * 32 + g * 8);
            float4 a = p[0], b = p[1];
            f16x8 v = { (f16)a.x,(f16)a.y,(f16)a.z,(f16)a.w,
                        (f16)b.x,(f16)b.y,(f16)b.z,(f16)b.w };
            w1f[ks][nt] = v;
        }
        #pragma unroll
        for (int ks = 0; ks < 4; ++ks) {
            const float4* p = reinterpret_cast<const float4*>(W2 + n * 128 + ks * 32 + g * 8);
            float4 a = p[0], b = p[1];
            f16x8 v = { (f16)a.x,(f16)a.y,(f16)a.z,(f16)a.w,
                        (f16)b.x,(f16)b.y,(f16)b.z,(f16)b.w };
            w2f[ks][nt] = v;
        }
        const int base = w * 32 + nt * 16 + g * 4;
        b1v[nt] = *reinterpret_cast<const f32x4*>(b1 + base);
        b2v[nt] = *reinterpret_cast<const f32x4*>(b2 + base);
        w3v[nt] = *reinterpret_cast<const f32x4*>(W3 + base);
    }
    const float b3s = b3[0];

    // ---------------- gather role: 2 threads per gathered node-row -------
    const int p_ = tid >> 1, q_ = tid & 1;   // p_: 0..127 node-rows, q_: 128B half
    const int m_ = p_ & 63;                  // edge within tile
    const int hh = p_ >> 6;                  // 0 = src half, 1 = dst half
    const int* __restrict__ idxArr = hh ? dstI : srcI;

    uint4 R[8];                              // prefetched 128B (8 x 16B chunks)
    int idxN2 = 0;

    auto loadIdx = [&](int t) -> int {
        int e = t * 64 + m_;
        return (e < E) ? idxArr[e] : 0;
    };
    auto issueGather = [&](int node) {
        if (USEF16) {
            const uint4* src = reinterpret_cast<const uint4*>(hf + (size_t)node * 128) + q_ * 8;
            #pragma unroll
            for (int j = 0; j < 8; ++j) R[j] = src[j];
        } else {
            const float4* src = reinterpret_cast<const float4*>(h32 + (size_t)node * 128) + q_ * 16;
            #pragma unroll
            for (int j = 0; j < 8; ++j) {
                float4 a = src[2 * j], b = src[2 * j + 1];
                f16x8 v = { (f16)a.x,(f16)a.y,(f16)a.z,(f16)a.w,
                            (f16)b.x,(f16)b.y,(f16)b.z,(f16)b.w };
                R[j] = *reinterpret_cast<uint4*>(&v);
            }
        }
    };
    auto writeLDS = [&]() {
        #pragma unroll
        for (int j = 0; j < 8; ++j) {
            int ch = hh * 16 + q_ * 8 + j;          // logical 16B chunk in 512B row
            int chs = ch ^ (m_ & 7);                // bank swizzle (low 3 bits)
            *reinterpret_cast<uint4*>(&heS[m_ * 256 + chs * 8]) = R[j];
        }
    };

    // ---------------- pipeline prologue ----------------
    const int t0 = blockIdx.x;
    if (t0 < ntiles) {
        issueGather(loadIdx(t0));
        writeLDS();                                  // stage tile t0
        if (t0 + grid < ntiles) issueGather(loadIdx(t0 + grid));       // R = t0+1
        idxN2 = (t0 + 2 * grid < ntiles) ? loadIdx(t0 + 2 * grid) : 0; // idx for t0+2
    }
    __syncthreads();

    int par = 0;
    for (int t = t0; t < ntiles; t += grid, par ^= 1) {
        // ---- GEMM1: acc1[et][nt], lane(g,c) -> x1[32w+16nt+4g+r][16et+c] ----
        f32x4 acc1[4][2];
        #pragma unroll
        for (int et = 0; et < 4; ++et) {
            acc1[et][0] = (f32x4){0.f,0.f,0.f,0.f};
            acc1[et][1] = (f32x4){0.f,0.f,0.f,0.f};
        }
        #pragma unroll
        for (int ks = 0; ks < 8; ++ks) {
            #pragma unroll
            for (int et = 0; et < 4; ++et) {
                const int edge = et * 16 + c;
                const int chs = (ks * 4 + g) ^ (edge & 7);
                f16x8 hb = *reinterpret_cast<const f16x8*>(&heS[edge * 256 + chs * 8]);
                acc1[et][0] = __builtin_amdgcn_mfma_f32_16x16x32_f16(w1f[ks][0], hb, acc1[et][0], 0, 0, 0);
                acc1[et][1] = __builtin_amdgcn_mfma_f32_16x16x32_f16(w1f[ks][1], hb, acc1[et][1], 0, 0, 0);
            }
        }

        // ---- bias + ReLU + packed b64 exchange writes ----
        #pragma unroll
        for (int et = 0; et < 4; ++et) {
            #pragma unroll
            for (int nt = 0; nt < 2; ++nt) {
                f32x4 v = acc1[et][nt] + b1v[nt];
                #pragma unroll
                for (int r = 0; r < 4; ++r) v[r] = v[r] > 0.f ? v[r] : 0.f;
                union { fp16x2 h2[2]; uint2 u; } uu;
                uu.h2[0] = __builtin_amdgcn_cvt_pkrtz(v[0], v[1]);
                uu.h2[1] = __builtin_amdgcn_cvt_pkrtz(v[2], v[3]);
                const int edge = et * 16 + c;
                const int n0 = w * 32 + nt * 16 + g * 4;       // natural n-order
                const int chs = (n0 >> 3) ^ (edge & 7);
                *reinterpret_cast<uint2*>(&x1S[edge * 128 + chs * 8 + (n0 & 7)]) = uu.u;
            }
        }
        __syncthreads();   // B1: x1S ready; heS free

        // ---- stage tile t+1 from prefetch regs; issue gathers for t+2 ----
        if (t + grid < ntiles) writeLDS();
        if (t + 2 * grid < ntiles) issueGather(idxN2);
        idxN2 = (t + 3 * grid < ntiles) ? loadIdx(t + 3 * grid) : 0;

        // ---- GEMM2 ----
        f32x4 acc2[4][2];
        #pragma unroll
        for (int et = 0; et < 4; ++et) {
            acc2[et][0] = (f32x4){0.f,0.f,0.f,0.f};
            acc2[et][1] = (f32x4){0.f,0.f,0.f,0.f};
        }
        #pragma unroll
        for (int ks = 0; ks < 4; ++ks) {
            #pragma unroll
            for (int et = 0; et < 4; ++et) {
                const int edge = et * 16 + c;
                const int chs = (ks * 4 + g) ^ (edge & 7);
                f16x8 xb = *reinterpret_cast<const f16x8*>(&x1S[edge * 128 + chs * 8]);
                acc2[et][0] = __builtin_amdgcn_mfma_f32_16x16x32_f16(w2f[ks][0], xb, acc2[et][0], 0, 0, 0);
                acc2[et][1] = __builtin_amdgcn_mfma_f32_16x16x32_f16(w2f[ks][1], xb, acc2[et][1], 0, 0, 0);
            }
        }

        // ---- layer 3 (fp32): relu(x2)+b2 dot w3, reduce over n2 ----
        #pragma unroll
        for (int et = 0; et < 4; ++et) {
            f32x4 sv = {0.f,0.f,0.f,0.f};
            #pragma unroll
            for (int nt = 0; nt < 2; ++nt) {
                f32x4 v = acc2[et][nt] + b2v[nt];
                #pragma unroll
                for (int r = 0; r < 4; ++r) {
                    float x = v[r] > 0.f ? v[r] : 0.f;
                    sv[r] += x * w3v[nt][r];
                }
            }
            float part = sv[0] + sv[1] + sv[2] + sv[3];
            part += __shfl_xor(part, 16, 64);
            part += __shfl_xor(part, 32, 64);
            if (g == 0) sbuf[par][w][et * 16 + c] = part;
        }
        __syncthreads();   // B2: sbuf ready, heS(t+1) written

        if (tid < 64) {
            const int e = t * 64 + tid;
            if (e < E)
                out[e] = sbuf[par][0][tid] + sbuf[par][1][tid]
                       + sbuf[par][2][tid] + sbuf[par][3][tid] + b3s;
        }
    }
}

// ---------------------------------------------------------------------------
extern "C" void kernel_launch(void* const* d_in, const int* in_sizes, int n_in,
                              void* d_out, int out_size, void* d_ws, size_t ws_size,
                              hipStream_t stream) {
    const float* h  = (const float*)d_in[0];
    const int* srcI = (const int*)d_in[1];
    const int* dstI = (const int*)d_in[2];
    const float* W1 = (const float*)d_in[3];
    const float* b1 = (const float*)d_in[4];
    const float* W2 = (const float*)d_in[5];
    const float* b2 = (const float*)d_in[6];
    const float* W3 = (const float*)d_in[7];
    const float* b3 = (const float*)d_in[8];
    float* out = (float*)d_out;

    const int E = in_sizes[1];
    const int hElems = in_sizes[0];
    f16* hf = (f16*)d_ws;
    const bool useF16 = (ws_size >= (size_t)hElems * sizeof(f16));

    if (useF16) cvt_h_f16<<<2048, 256, 0, stream>>>(h, hf, hElems / 4);

    const int ntiles = (E + 63) / 64;
    const int grid = ntiles < 768 ? ntiles : 768;   // 3 blocks/CU (LDS 50 KB)
    if (useF16)
        mlp_edges<1><<<grid, 256, 0, stream>>>(h, hf, srcI, dstI, W1, b1, W2, b2, W3, b3, out, E, ntiles);
    else
        mlp_edges<0><<<grid, 256, 0, stream>>>(h, hf, srcI, dstI, W1, b1, W2, b2, W3, b3, out, E, ntiles);
}

// Round 7
// 311.329 us; speedup vs baseline: 1.3091x; 1.3091x over previous
//
#include <hip/hip_runtime.h>
#include <hip/hip_fp16.h>

typedef _Float16 f16;
typedef __attribute__((ext_vector_type(8))) _Float16 f16x8;
typedef __attribute__((ext_vector_type(4))) _Float16 f16x4;
typedef __attribute__((ext_vector_type(2))) __fp16 fp16x2;   // cvt_pkrtz return type
typedef __attribute__((ext_vector_type(4))) float f32x4;

// ---------------------------------------------------------------------------
// Pre-pass: h (fp32) -> f16 copy in workspace (halves gather bytes).
// ---------------------------------------------------------------------------
__global__ void cvt_h_f16(const float* __restrict__ h, f16* __restrict__ hf, int n4) {
    int stride = gridDim.x * blockDim.x;
    for (int i = blockIdx.x * blockDim.x + threadIdx.x; i < n4; i += stride) {
        float4 v = reinterpret_cast<const float4*>(h)[i];
        f16x4 o = { (f16)v.x, (f16)v.y, (f16)v.z, (f16)v.w };
        reinterpret_cast<f16x4*>(hf)[i] = o;
    }
}

// ---------------------------------------------------------------------------
// Fused edge-MLP, swapped-operand MFMA (A = weights in regs, B = data in LDS).
//   Block: 64 edges, 4 waves. Wave w owns feature rows [32w, 32w+32).
//   Round-1 proven phase structure (stage -> B0 -> GEMM1 -> x1 -> B1 ->
//   GEMM2 -> layer3 -> B2 -> store), 3 barriers/tile.
// Register budget for 3 waves/SIMD (<=170 unified):
//   w1f 64 + w2f 32 + SHARED acc 32 (AGPR, reused GEMM1->GEMM2) + misc ~20.
//   __launch_bounds__(256,3): 12 waves/CU (was 8) -> stall hiding +50%.
// Only the edge-index load is prefetched (1 scalar during GEMM1) — removes
// the idx->gather serial hop; NO row prefetch (round-3 regression, reverted).
// ---------------------------------------------------------------------------
template<int USEF16>
__global__ __launch_bounds__(256, 3)
void mlp_edges(const float* __restrict__ h32, const f16* __restrict__ hf,
               const int* __restrict__ srcI, const int* __restrict__ dstI,
               const float* __restrict__ W1, const float* __restrict__ b1,
               const float* __restrict__ W2, const float* __restrict__ b2,
               const float* __restrict__ W3, const float* __restrict__ b3,
               float* __restrict__ out, int E, int ntiles)
{
    __shared__ f16 heS[64 * 256];      // 32 KB: [edge][k=256 f16], 16B-chunk swizzled
    __shared__ f16 x1S[64 * 128];      // 16 KB: [edge][n=128 f16], swizzled
    __shared__ float sbuf[4][64];      // 1 KB

    const int tid = threadIdx.x;
    const int w = tid >> 6, l = tid & 63, g = l >> 4, c = l & 15;
    const int grid = gridDim.x;

    // ---------------- weight fragments (registers, once) ----------------
    f16x8 w1f[8][2], w2f[4][2];
    f32x4 b1v[2], b2v[2], w3v[2];
    #pragma unroll
    for (int nt = 0; nt < 2; ++nt) {
        const int n = w * 32 + nt * 16 + c;
        #pragma unroll
        for (int ks = 0; ks < 8; ++ks) {
            const float4* p = reinterpret_cast<const float4*>(W1 + n * 256 + ks * 32 + g * 8);
            float4 a = p[0], b = p[1];
            f16x8 v = { (f16)a.x,(f16)a.y,(f16)a.z,(f16)a.w,
                        (f16)b.x,(f16)b.y,(f16)b.z,(f16)b.w };
            w1f[ks][nt] = v;
        }
        #pragma unroll
        for (int ks = 0; ks < 4; ++ks) {
            const float4* p = reinterpret_cast<const float4*>(W2 + n * 128 + ks * 32 + g * 8);
            float4 a = p[0], b = p[1];
            f16x8 v = { (f16)a.x,(f16)a.y,(f16)a.z,(f16)a.w,
                        (f16)b.x,(f16)b.y,(f16)b.z,(f16)b.w };
            w2f[ks][nt] = v;
        }
        const int base = w * 32 + nt * 16 + g * 4;
        b1v[nt] = *reinterpret_cast<const f32x4*>(b1 + base);
        b2v[nt] = *reinterpret_cast<const f32x4*>(b2 + base);
        w3v[nt] = *reinterpret_cast<const f32x4*>(W3 + base);
    }
    const float b3s = b3[0];

    // ---------------- gather role: 2 threads per gathered node-row -------
    const int p_ = tid >> 1, q_ = tid & 1;   // p_: 0..127 node-rows, q_: 128B half
    const int m_ = p_ & 63;                  // edge within tile
    const int hh = p_ >> 6;                  // 0 = src half, 1 = dst half
    const int* __restrict__ idxArr = hh ? dstI : srcI;

    auto loadIdx = [&](int t) -> int {
        int e = t * 64 + m_;
        return (e < E) ? idxArr[e] : 0;
    };
    auto stage = [&](int node) {
        if (USEF16) {
            const uint4* src = reinterpret_cast<const uint4*>(hf + (size_t)node * 128) + q_ * 8;
            #pragma unroll
            for (int j = 0; j < 8; ++j) {
                uint4 v = src[j];
                const int chs = (hh * 16 + q_ * 8 + j) ^ (m_ & 7);
                *reinterpret_cast<uint4*>(&heS[m_ * 256 + chs * 8]) = v;
            }
        } else {
            const float4* src = reinterpret_cast<const float4*>(h32 + (size_t)node * 128) + q_ * 16;
            #pragma unroll
            for (int j = 0; j < 8; ++j) {
                float4 a = src[2 * j], b = src[2 * j + 1];
                f16x8 v = { (f16)a.x,(f16)a.y,(f16)a.z,(f16)a.w,
                            (f16)b.x,(f16)b.y,(f16)b.z,(f16)b.w };
                const int chs = (hh * 16 + q_ * 8 + j) ^ (m_ & 7);
                *reinterpret_cast<f16x8*>(&heS[m_ * 256 + chs * 8]) = v;
            }
        }
    };

    const int t0 = blockIdx.x;
    int nIdx = (t0 < ntiles) ? loadIdx(t0) : 0;

    for (int t = t0; t < ntiles; t += grid) {
        // ---- stage he tile (uses prefetched index) ----
        stage(nIdx);
        __syncthreads();   // B0: heS ready

        // prefetch next tile's index during compute (1 scalar load)
        nIdx = (t + grid < ntiles) ? loadIdx(t + grid) : 0;

        // ---- GEMM1: acc[et][nt], lane(g,c) -> x1[32w+16nt+4g+r][16et+c] ----
        f32x4 acc[4][2];
        #pragma unroll
        for (int et = 0; et < 4; ++et) {
            acc[et][0] = (f32x4){0.f,0.f,0.f,0.f};
            acc[et][1] = (f32x4){0.f,0.f,0.f,0.f};
        }
        #pragma unroll
        for (int ks = 0; ks < 8; ++ks) {
            #pragma unroll
            for (int et = 0; et < 4; ++et) {
                const int edge = et * 16 + c;
                const int chs = (ks * 4 + g) ^ (edge & 7);
                f16x8 hb = *reinterpret_cast<const f16x8*>(&heS[edge * 256 + chs * 8]);
                acc[et][0] = __builtin_amdgcn_mfma_f32_16x16x32_f16(w1f[ks][0], hb, acc[et][0], 0, 0, 0);
                acc[et][1] = __builtin_amdgcn_mfma_f32_16x16x32_f16(w1f[ks][1], hb, acc[et][1], 0, 0, 0);
            }
        }

        // ---- bias + ReLU + packed b64 exchange writes ----
        #pragma unroll
        for (int et = 0; et < 4; ++et) {
            #pragma unroll
            for (int nt = 0; nt < 2; ++nt) {
                f32x4 v = acc[et][nt] + b1v[nt];
                #pragma unroll
                for (int r = 0; r < 4; ++r) v[r] = v[r] > 0.f ? v[r] : 0.f;
                union { fp16x2 h2[2]; uint2 u; } uu;
                uu.h2[0] = __builtin_amdgcn_cvt_pkrtz(v[0], v[1]);
                uu.h2[1] = __builtin_amdgcn_cvt_pkrtz(v[2], v[3]);
                const int edge = et * 16 + c;
                const int n0 = w * 32 + nt * 16 + g * 4;       // natural n-order
                const int chs = (n0 >> 3) ^ (edge & 7);
                *reinterpret_cast<uint2*>(&x1S[edge * 128 + chs * 8 + (n0 & 7)]) = uu.u;
            }
        }
        __syncthreads();   // B1: x1S ready

        // ---- GEMM2 (acc reused: re-zeroed) ----
        #pragma unroll
        for (int et = 0; et < 4; ++et) {
            acc[et][0] = (f32x4){0.f,0.f,0.f,0.f};
            acc[et][1] = (f32x4){0.f,0.f,0.f,0.f};
        }
        #pragma unroll
        for (int ks = 0; ks < 4; ++ks) {
            #pragma unroll
            for (int et = 0; et < 4; ++et) {
                const int edge = et * 16 + c;
                const int chs = (ks * 4 + g) ^ (edge & 7);
                f16x8 xb = *reinterpret_cast<const f16x8*>(&x1S[edge * 128 + chs * 8]);
                acc[et][0] = __builtin_amdgcn_mfma_f32_16x16x32_f16(w2f[ks][0], xb, acc[et][0], 0, 0, 0);
                acc[et][1] = __builtin_amdgcn_mfma_f32_16x16x32_f16(w2f[ks][1], xb, acc[et][1], 0, 0, 0);
            }
        }

        // ---- layer 3 (fp32): relu(x2)+b2 dot w3, reduce over n2 ----
        #pragma unroll
        for (int et = 0; et < 4; ++et) {
            f32x4 sv = {0.f,0.f,0.f,0.f};
            #pragma unroll
            for (int nt = 0; nt < 2; ++nt) {
                f32x4 v = acc[et][nt] + b2v[nt];
                #pragma unroll
                for (int r = 0; r < 4; ++r) {
                    float x = v[r] > 0.f ? v[r] : 0.f;
                    sv[r] += x * w3v[nt][r];
                }
            }
            float part = sv[0] + sv[1] + sv[2] + sv[3];
            part += __shfl_xor(part, 16, 64);
            part += __shfl_xor(part, 32, 64);
            if (g == 0) sbuf[w][et * 16 + c] = part;
        }
        __syncthreads();   // B2: sbuf ready; heS/x1S free for next tile

        if (tid < 64) {
            const int e = t * 64 + tid;
            if (e < E)
                out[e] = sbuf[0][tid] + sbuf[1][tid] + sbuf[2][tid] + sbuf[3][tid] + b3s;
        }
        // next staging (after loop-top) only overwrites heS, which GEMM1
        // consumes post-B0; sbuf reads complete before next layer3 (B0+B1).
    }
}

// ---------------------------------------------------------------------------
extern "C" void kernel_launch(void* const* d_in, const int* in_sizes, int n_in,
                              void* d_out, int out_size, void* d_ws, size_t ws_size,
                              hipStream_t stream) {
    const float* h  = (const float*)d_in[0];
    const int* srcI = (const int*)d_in[1];
    const int* dstI = (const int*)d_in[2];
    const float* W1 = (const float*)d_in[3];
    const float* b1 = (const float*)d_in[4];
    const float* W2 = (const float*)d_in[5];
    const float* b2 = (const float*)d_in[6];
    const float* W3 = (const float*)d_in[7];
    const float* b3 = (const float*)d_in[8];
    float* out = (float*)d_out;

    const int E = in_sizes[1];
    const int hElems = in_sizes[0];
    f16* hf = (f16*)d_ws;
    const bool useF16 = (ws_size >= (size_t)hElems * sizeof(f16));

    if (useF16) cvt_h_f16<<<2048, 256, 0, stream>>>(h, hf, hElems / 4);

    const int ntiles = (E + 63) / 64;
    const int grid = ntiles < 768 ? ntiles : 768;   // 3 blocks/CU (LDS 49 KB, 3 waves/SIMD)
    if (useF16)
        mlp_edges<1><<<grid, 256, 0, stream>>>(h, hf, srcI, dstI, W1, b1, W2, b2, W3, b3, out, E, ntiles);
    else
        mlp_edges<0><<<grid, 256, 0, stream>>>(h, hf, srcI, dstI, W1, b1, W2, b2, W3, b3, out, E, ntiles);
}

// Round 8
// 181.992 us; speedup vs baseline: 2.2394x; 1.7107x over previous
//
#include <hip/hip_runtime.h>
#include <hip/hip_fp16.h>

typedef _Float16 f16;
typedef __attribute__((ext_vector_type(8))) _Float16 f16x8;
typedef __attribute__((ext_vector_type(4))) _Float16 f16x4;
typedef __attribute__((ext_vector_type(2))) __fp16 fp16x2;
typedef __attribute__((ext_vector_type(4))) float f32x4;

// ---------------------------------------------------------------------------
// Pre-pass A (fallback only): h (fp32) -> f16.
// ---------------------------------------------------------------------------
__global__ void cvt_h_f16(const float* __restrict__ h, f16* __restrict__ hf, int n4) {
    int stride = gridDim.x * blockDim.x;
    for (int i = blockIdx.x * blockDim.x + threadIdx.x; i < n4; i += stride) {
        float4 v = reinterpret_cast<const float4*>(h)[i];
        f16x4 o = { (f16)v.x, (f16)v.y, (f16)v.z, (f16)v.w };
        reinterpret_cast<f16x4*>(hf)[i] = o;
    }
}

// ---------------------------------------------------------------------------
// Pre-pass B: per-node layer-1 halves.
//   u[n] = W1[:, :128] @ h[n] + b1   (bias folded into u)
//   v[n] = W1[:,128:] @ h[n]
// Node-major, coalesced. 64 nodes/block, 4 waves, swapped-operand MFMA.
// ---------------------------------------------------------------------------
__global__ __launch_bounds__(256, 2)
void build_uv(const float* __restrict__ h, const float* __restrict__ W1,
              const float* __restrict__ b1,
              f16* __restrict__ U, f16* __restrict__ V, int nNodes)
{
    __shared__ f16 hS[64 * 128];   // 16 KB staged h tile (f16), 16B-chunk swizzled
    __shared__ f16 xS[64 * 128];   // 16 KB exchange

    const int tid = threadIdx.x;
    const int w = tid >> 6, l = tid & 63, g = l >> 4, c = l & 15;

    // A-fragments: wave w owns output rows [32w, 32w+32) of both halves.
    f16x8 waf[4][2], wbf[4][2];
    f32x4 b1v[2];
    #pragma unroll
    for (int nt = 0; nt < 2; ++nt) {
        const int n = w * 32 + nt * 16 + c;
        #pragma unroll
        for (int ks = 0; ks < 4; ++ks) {
            const float4* pa = reinterpret_cast<const float4*>(W1 + n * 256 + ks * 32 + g * 8);
            const float4* pb = reinterpret_cast<const float4*>(W1 + n * 256 + 128 + ks * 32 + g * 8);
            float4 a0 = pa[0], a1 = pa[1], b0 = pb[0], b1_ = pb[1];
            f16x8 va = { (f16)a0.x,(f16)a0.y,(f16)a0.z,(f16)a0.w,
                         (f16)a1.x,(f16)a1.y,(f16)a1.z,(f16)a1.w };
            f16x8 vb = { (f16)b0.x,(f16)b0.y,(f16)b0.z,(f16)b0.w,
                         (f16)b1_.x,(f16)b1_.y,(f16)b1_.z,(f16)b1_.w };
            waf[ks][nt] = va;
            wbf[ks][nt] = vb;
        }
        b1v[nt] = *reinterpret_cast<const f32x4*>(b1 + w * 32 + nt * 16 + g * 4);
    }

    const int node0 = blockIdx.x * 64;
    // ---- stage h rows: 4 threads per row (128B f32 each -> 4 f16 chunks) ----
    {
        const int m = tid >> 2, q4 = tid & 3;
        const int node = node0 + m;
        if (node < nNodes) {
            const float4* src = reinterpret_cast<const float4*>(h + (size_t)node * 128) + q4 * 8;
            #pragma unroll
            for (int j = 0; j < 4; ++j) {
                float4 a = src[2 * j], b = src[2 * j + 1];
                f16x8 v = { (f16)a.x,(f16)a.y,(f16)a.z,(f16)a.w,
                            (f16)b.x,(f16)b.y,(f16)b.z,(f16)b.w };
                const int chs = (q4 * 4 + j) ^ (m & 7);
                *reinterpret_cast<f16x8*>(&hS[m * 128 + chs * 8]) = v;
            }
        } else {
            #pragma unroll
            for (int j = 0; j < 4; ++j) {
                const int chs = (q4 * 4 + j) ^ (m & 7);
                *reinterpret_cast<f16x8*>(&hS[m * 128 + chs * 8]) = (f16x8)(f16)0;
            }
        }
    }
    __syncthreads();

    f32x4 acc[4][2];
    // ================= matrix U =================
    #pragma unroll
    for (int et = 0; et < 4; ++et) { acc[et][0] = (f32x4){0,0,0,0}; acc[et][1] = (f32x4){0,0,0,0}; }
    #pragma unroll
    for (int ks = 0; ks < 4; ++ks) {
        #pragma unroll
        for (int et = 0; et < 4; ++et) {
            const int row = et * 16 + c;
            const int chs = (ks * 4 + g) ^ (row & 7);
            f16x8 hb = *reinterpret_cast<const f16x8*>(&hS[row * 128 + chs * 8]);
            acc[et][0] = __builtin_amdgcn_mfma_f32_16x16x32_f16(waf[ks][0], hb, acc[et][0], 0, 0, 0);
            acc[et][1] = __builtin_amdgcn_mfma_f32_16x16x32_f16(waf[ks][1], hb, acc[et][1], 0, 0, 0);
        }
    }
    // +b1, pack RTE, exchange
    #pragma unroll
    for (int et = 0; et < 4; ++et) {
        #pragma unroll
        for (int nt = 0; nt < 2; ++nt) {
            f32x4 v = acc[et][nt] + b1v[nt];
            f16x4 p = { (f16)v[0], (f16)v[1], (f16)v[2], (f16)v[3] };
            const int row = et * 16 + c;
            const int n0 = w * 32 + nt * 16 + g * 4;
            const int chs = (n0 >> 3) ^ (row & 7);
            *reinterpret_cast<f16x4*>(&xS[row * 128 + chs * 8 + (n0 & 7)]) = p;
        }
    }
    __syncthreads();
    // coalesced store U
    {
        const int m = tid >> 2, q4 = tid & 3;
        const int node = node0 + m;
        if (node < nNodes) {
            #pragma unroll
            for (int j = 0; j < 4; ++j) {
                const int lc = q4 * 4 + j;
                const int chs = lc ^ (m & 7);
                uint4 val = *reinterpret_cast<const uint4*>(&xS[m * 128 + chs * 8]);
                reinterpret_cast<uint4*>(U + (size_t)node * 128)[lc] = val;
            }
        }
    }
    __syncthreads();   // xS free

    // ================= matrix V =================
    #pragma unroll
    for (int et = 0; et < 4; ++et) { acc[et][0] = (f32x4){0,0,0,0}; acc[et][1] = (f32x4){0,0,0,0}; }
    #pragma unroll
    for (int ks = 0; ks < 4; ++ks) {
        #pragma unroll
        for (int et = 0; et < 4; ++et) {
            const int row = et * 16 + c;
            const int chs = (ks * 4 + g) ^ (row & 7);
            f16x8 hb = *reinterpret_cast<const f16x8*>(&hS[row * 128 + chs * 8]);
            acc[et][0] = __builtin_amdgcn_mfma_f32_16x16x32_f16(wbf[ks][0], hb, acc[et][0], 0, 0, 0);
            acc[et][1] = __builtin_amdgcn_mfma_f32_16x16x32_f16(wbf[ks][1], hb, acc[et][1], 0, 0, 0);
        }
    }
    #pragma unroll
    for (int et = 0; et < 4; ++et) {
        #pragma unroll
        for (int nt = 0; nt < 2; ++nt) {
            f32x4 v = acc[et][nt];
            f16x4 p = { (f16)v[0], (f16)v[1], (f16)v[2], (f16)v[3] };
            const int row = et * 16 + c;
            const int n0 = w * 32 + nt * 16 + g * 4;
            const int chs = (n0 >> 3) ^ (row & 7);
            *reinterpret_cast<f16x4*>(&xS[row * 128 + chs * 8 + (n0 & 7)]) = p;
        }
    }
    __syncthreads();
    {
        const int m = tid >> 2, q4 = tid & 3;
        const int node = node0 + m;
        if (node < nNodes) {
            #pragma unroll
            for (int j = 0; j < 4; ++j) {
                const int lc = q4 * 4 + j;
                const int chs = lc ^ (m & 7);
                uint4 val = *reinterpret_cast<const uint4*>(&xS[m * 128 + chs * 8]);
                reinterpret_cast<uint4*>(V + (size_t)node * 128)[lc] = val;
            }
        }
    }
}

// ---------------------------------------------------------------------------
// Edge kernel (u/v form): per tile of 64 edges,
//   gather u[src], v[dst] -> LDS;  x1 = relu(u+v) in packed f16 (b1 already
//   in u);  GEMM2 (W2 frags in regs, x1 B-frags fused add);  layer3 fp32.
// 2 barriers/tile; LDS 33 KB; 4 blocks/CU target.
// ---------------------------------------------------------------------------
__global__ __launch_bounds__(256, 4)
void mlp_edges_uv(const f16* __restrict__ U, const f16* __restrict__ V,
                  const int* __restrict__ srcI, const int* __restrict__ dstI,
                  const float* __restrict__ W2, const float* __restrict__ b2,
                  const float* __restrict__ W3, const float* __restrict__ b3,
                  float* __restrict__ out, int E, int ntiles)
{
    __shared__ f16 uS[64 * 128];   // 16 KB [edge][n1=128], 16B-chunk swizzled
    __shared__ f16 vS[64 * 128];   // 16 KB
    __shared__ float sbuf[4][64];  // 1 KB

    const int tid = threadIdx.x;
    const int w = tid >> 6, l = tid & 63, g = l >> 4, c = l & 15;
    const int grid = gridDim.x;

    // ---- W2 fragments + layer-3 constants ----
    f16x8 w2f[4][2];
    f32x4 b2v[2], w3v[2];
    #pragma unroll
    for (int nt = 0; nt < 2; ++nt) {
        const int n = w * 32 + nt * 16 + c;
        #pragma unroll
        for (int ks = 0; ks < 4; ++ks) {
            const float4* p = reinterpret_cast<const float4*>(W2 + n * 128 + ks * 32 + g * 8);
            float4 a = p[0], b = p[1];
            f16x8 v = { (f16)a.x,(f16)a.y,(f16)a.z,(f16)a.w,
                        (f16)b.x,(f16)b.y,(f16)b.z,(f16)b.w };
            w2f[ks][nt] = v;
        }
        const int base = w * 32 + nt * 16 + g * 4;
        b2v[nt] = *reinterpret_cast<const f32x4*>(b2 + base);
        w3v[nt] = *reinterpret_cast<const f32x4*>(W3 + base);
    }
    const float b3s = b3[0];

    // ---- gather roles: 2 threads per 256B row; 64 u-rows + 64 v-rows ----
    const int p_ = tid >> 1, q_ = tid & 1;
    const int m_ = p_ & 63;
    const int hh = p_ >> 6;                    // 0 = u (src), 1 = v (dst)
    const int* __restrict__ idxArr = hh ? dstI : srcI;
    const f16* __restrict__ tab = hh ? V : U;
    f16* dstS = hh ? vS : uS;

    auto loadIdx = [&](int t) -> int {
        int e = t * 64 + m_;
        return (e < E) ? idxArr[e] : 0;
    };
    auto stage = [&](int node) {
        const uint4* src = reinterpret_cast<const uint4*>(tab + (size_t)node * 128) + q_ * 8;
        #pragma unroll
        for (int j = 0; j < 8; ++j) {
            uint4 v = src[j];
            const int chs = (q_ * 8 + j) ^ (m_ & 7);
            *reinterpret_cast<uint4*>(&dstS[m_ * 128 + chs * 8]) = v;
        }
    };

    const int t0 = blockIdx.x;
    int nIdx = (t0 < ntiles) ? loadIdx(t0) : 0;

    for (int t = t0; t < ntiles; t += grid) {
        stage(nIdx);
        __syncthreads();   // B0: uS/vS ready
        nIdx = (t + grid < ntiles) ? loadIdx(t + grid) : 0;

        // ---- GEMM2 with fused x1 = relu(u+v) B-fragments ----
        f32x4 acc[4][2];
        #pragma unroll
        for (int et = 0; et < 4; ++et) { acc[et][0] = (f32x4){0,0,0,0}; acc[et][1] = (f32x4){0,0,0,0}; }
        #pragma unroll
        for (int ks = 0; ks < 4; ++ks) {
            #pragma unroll
            for (int et = 0; et < 4; ++et) {
                const int edge = et * 16 + c;
                const int chs = (ks * 4 + g) ^ (edge & 7);
                f16x8 uf = *reinterpret_cast<const f16x8*>(&uS[edge * 128 + chs * 8]);
                f16x8 vf = *reinterpret_cast<const f16x8*>(&vS[edge * 128 + chs * 8]);
                f16x8 xf = uf + vf;                       // v_pk_add_f16
                #pragma unroll
                for (int j = 0; j < 8; ++j) xf[j] = xf[j] > (f16)0 ? xf[j] : (f16)0;
                acc[et][0] = __builtin_amdgcn_mfma_f32_16x16x32_f16(w2f[ks][0], xf, acc[et][0], 0, 0, 0);
                acc[et][1] = __builtin_amdgcn_mfma_f32_16x16x32_f16(w2f[ks][1], xf, acc[et][1], 0, 0, 0);
            }
        }

        // ---- layer 3 (fp32) + reduce ----
        #pragma unroll
        for (int et = 0; et < 4; ++et) {
            f32x4 sv = {0.f,0.f,0.f,0.f};
            #pragma unroll
            for (int nt = 0; nt < 2; ++nt) {
                f32x4 v = acc[et][nt] + b2v[nt];
                #pragma unroll
                for (int r = 0; r < 4; ++r) {
                    float x = v[r] > 0.f ? v[r] : 0.f;
                    sv[r] += x * w3v[nt][r];
                }
            }
            float part = sv[0] + sv[1] + sv[2] + sv[3];
            part += __shfl_xor(part, 16, 64);
            part += __shfl_xor(part, 32, 64);
            if (g == 0) sbuf[w][et * 16 + c] = part;
        }
        __syncthreads();   // B1: sbuf ready; uS/vS free

        if (tid < 64) {
            const int e = t * 64 + tid;
            if (e < E)
                out[e] = sbuf[0][tid] + sbuf[1][tid] + sbuf[2][tid] + sbuf[3][tid] + b3s;
        }
        // sbuf reads finish before next tile's sbuf writes (which follow B0).
    }
}

// ---------------------------------------------------------------------------
// Fallback (ws too small for U+V): round-7 proven kernel.
// ---------------------------------------------------------------------------
template<int USEF16>
__global__ __launch_bounds__(256, 3)
void mlp_edges(const float* __restrict__ h32, const f16* __restrict__ hf,
               const int* __restrict__ srcI, const int* __restrict__ dstI,
               const float* __restrict__ W1, const float* __restrict__ b1,
               const float* __restrict__ W2, const float* __restrict__ b2,
               const float* __restrict__ W3, const float* __restrict__ b3,
               float* __restrict__ out, int E, int ntiles)
{
    __shared__ f16 heS[64 * 256];
    __shared__ f16 x1S[64 * 128];
    __shared__ float sbuf[4][64];

    const int tid = threadIdx.x;
    const int w = tid >> 6, l = tid & 63, g = l >> 4, c = l & 15;
    const int grid = gridDim.x;

    f16x8 w1f[8][2], w2f[4][2];
    f32x4 b1v[2], b2v[2], w3v[2];
    #pragma unroll
    for (int nt = 0; nt < 2; ++nt) {
        const int n = w * 32 + nt * 16 + c;
        #pragma unroll
        for (int ks = 0; ks < 8; ++ks) {
            const float4* p = reinterpret_cast<const float4*>(W1 + n * 256 + ks * 32 + g * 8);
            float4 a = p[0], b = p[1];
            f16x8 v = { (f16)a.x,(f16)a.y,(f16)a.z,(f16)a.w,
                        (f16)b.x,(f16)b.y,(f16)b.z,(f16)b.w };
            w1f[ks][nt] = v;
        }
        #pragma unroll
        for (int ks = 0; ks < 4; ++ks) {
            const float4* p = reinterpret_cast<const float4*>(W2 + n * 128 + ks * 32 + g * 8);
            float4 a = p[0], b = p[1];
            f16x8 v = { (f16)a.x,(f16)a.y,(f16)a.z,(f16)a.w,
                        (f16)b.x,(f16)b.y,(f16)b.z,(f16)b.w };
            w2f[ks][nt] = v;
        }
        const int base = w * 32 + nt * 16 + g * 4;
        b1v[nt] = *reinterpret_cast<const f32x4*>(b1 + base);
        b2v[nt] = *reinterpret_cast<const f32x4*>(b2 + base);
        w3v[nt] = *reinterpret_cast<const f32x4*>(W3 + base);
    }
    const float b3s = b3[0];

    const int p_ = tid >> 1, q_ = tid & 1;
    const int m_ = p_ & 63;
    const int hh = p_ >> 6;
    const int* __restrict__ idxArr = hh ? dstI : srcI;

    auto loadIdx = [&](int t) -> int {
        int e = t * 64 + m_;
        return (e < E) ? idxArr[e] : 0;
    };
    auto stage = [&](int node) {
        if (USEF16) {
            const uint4* src = reinterpret_cast<const uint4*>(hf + (size_t)node * 128) + q_ * 8;
            #pragma unroll
            for (int j = 0; j < 8; ++j) {
                uint4 v = src[j];
                const int chs = (hh * 16 + q_ * 8 + j) ^ (m_ & 7);
                *reinterpret_cast<uint4*>(&heS[m_ * 256 + chs * 8]) = v;
            }
        } else {
            const float4* src = reinterpret_cast<const float4*>(h32 + (size_t)node * 128) + q_ * 16;
            #pragma unroll
            for (int j = 0; j < 8; ++j) {
                float4 a = src[2 * j], b = src[2 * j + 1];
                f16x8 v = { (f16)a.x,(f16)a.y,(f16)a.z,(f16)a.w,
                            (f16)b.x,(f16)b.y,(f16)b.z,(f16)b.w };
                const int chs = (hh * 16 + q_ * 8 + j) ^ (m_ & 7);
                *reinterpret_cast<f16x8*>(&heS[m_ * 256 + chs * 8]) = v;
            }
        }
    };

    const int t0 = blockIdx.x;
    int nIdx = (t0 < ntiles) ? loadIdx(t0) : 0;

    for (int t = t0; t < ntiles; t += grid) {
        stage(nIdx);
        __syncthreads();
        nIdx = (t + grid < ntiles) ? loadIdx(t + grid) : 0;

        f32x4 acc[4][2];
        #pragma unroll
        for (int et = 0; et < 4; ++et) { acc[et][0] = (f32x4){0,0,0,0}; acc[et][1] = (f32x4){0,0,0,0}; }
        #pragma unroll
        for (int ks = 0; ks < 8; ++ks) {
            #pragma unroll
            for (int et = 0; et < 4; ++et) {
                const int edge = et * 16 + c;
                const int chs = (ks * 4 + g) ^ (edge & 7);
                f16x8 hb = *reinterpret_cast<const f16x8*>(&heS[edge * 256 + chs * 8]);
                acc[et][0] = __builtin_amdgcn_mfma_f32_16x16x32_f16(w1f[ks][0], hb, acc[et][0], 0, 0, 0);
                acc[et][1] = __builtin_amdgcn_mfma_f32_16x16x32_f16(w1f[ks][1], hb, acc[et][1], 0, 0, 0);
            }
        }
        #pragma unroll
        for (int et = 0; et < 4; ++et) {
            #pragma unroll
            for (int nt = 0; nt < 2; ++nt) {
                f32x4 v = acc[et][nt] + b1v[nt];
                #pragma unroll
                for (int r = 0; r < 4; ++r) v[r] = v[r] > 0.f ? v[r] : 0.f;
                union { fp16x2 h2[2]; uint2 u; } uu;
                uu.h2[0] = __builtin_amdgcn_cvt_pkrtz(v[0], v[1]);
                uu.h2[1] = __builtin_amdgcn_cvt_pkrtz(v[2], v[3]);
                const int edge = et * 16 + c;
                const int n0 = w * 32 + nt * 16 + g * 4;
                const int chs = (n0 >> 3) ^ (edge & 7);
                *reinterpret_cast<uint2*>(&x1S[edge * 128 + chs * 8 + (n0 & 7)]) = uu.u;
            }
        }
        __syncthreads();

        #pragma unroll
        for (int et = 0; et < 4; ++et) { acc[et][0] = (f32x4){0,0,0,0}; acc[et][1] = (f32x4){0,0,0,0}; }
        #pragma unroll
        for (int ks = 0; ks < 4; ++ks) {
            #pragma unroll
            for (int et = 0; et < 4; ++et) {
                const int edge = et * 16 + c;
                const int chs = (ks * 4 + g) ^ (edge & 7);
                f16x8 xb = *reinterpret_cast<const f16x8*>(&x1S[edge * 128 + chs * 8]);
                acc[et][0] = __builtin_amdgcn_mfma_f32_16x16x32_f16(w2f[ks][0], xb, acc[et][0], 0, 0, 0);
                acc[et][1] = __builtin_amdgcn_mfma_f32_16x16x32_f16(w2f[ks][1], xb, acc[et][1], 0, 0, 0);
            }
        }
        #pragma unroll
        for (int et = 0; et < 4; ++et) {
            f32x4 sv = {0.f,0.f,0.f,0.f};
            #pragma unroll
            for (int nt = 0; nt < 2; ++nt) {
                f32x4 v = acc[et][nt] + b2v[nt];
                #pragma unroll
                for (int r = 0; r < 4; ++r) {
                    float x = v[r] > 0.f ? v[r] : 0.f;
                    sv[r] += x * w3v[nt][r];
                }
            }
            float part = sv[0] + sv[1] + sv[2] + sv[3];
            part += __shfl_xor(part, 16, 64);
            part += __shfl_xor(part, 32, 64);
            if (g == 0) sbuf[w][et * 16 + c] = part;
        }
        __syncthreads();

        if (tid < 64) {
            const int e = t * 64 + tid;
            if (e < E)
                out[e] = sbuf[0][tid] + sbuf[1][tid] + sbuf[2][tid] + sbuf[3][tid] + b3s;
        }
    }
}

// ---------------------------------------------------------------------------
extern "C" void kernel_launch(void* const* d_in, const int* in_sizes, int n_in,
                              void* d_out, int out_size, void* d_ws, size_t ws_size,
                              hipStream_t stream) {
    const float* h  = (const float*)d_in[0];
    const int* srcI = (const int*)d_in[1];
    const int* dstI = (const int*)d_in[2];
    const float* W1 = (const float*)d_in[3];
    const float* b1 = (const float*)d_in[4];
    const float* W2 = (const float*)d_in[5];
    const float* b2 = (const float*)d_in[6];
    const float* W3 = (const float*)d_in[7];
    const float* b3 = (const float*)d_in[8];
    float* out = (float*)d_out;

    const int E = in_sizes[1];
    const int hElems = in_sizes[0];        // nNodes * 128
    const int nNodes = hElems / 128;
    const int ntiles = (E + 63) / 64;

    const size_t uvBytes = 2 * (size_t)nNodes * 128 * sizeof(f16);   // U + V
    if (ws_size >= uvBytes) {
        f16* U = (f16*)d_ws;
        f16* V = U + (size_t)nNodes * 128;
        build_uv<<<(nNodes + 63) / 64, 256, 0, stream>>>(h, W1, b1, U, V, nNodes);
        const int grid = ntiles < 1024 ? ntiles : 1024;   // 4 blocks/CU
        mlp_edges_uv<<<grid, 256, 0, stream>>>(U, V, srcI, dstI, W2, b2, W3, b3, out, E, ntiles);
    } else {
        f16* hf = (f16*)d_ws;
        const bool useF16 = (ws_size >= (size_t)hElems * sizeof(f16));
        if (useF16) cvt_h_f16<<<2048, 256, 0, stream>>>(h, hf, hElems / 4);
        const int grid = ntiles < 768 ? ntiles : 768;
        if (useF16)
            mlp_edges<1><<<grid, 256, 0, stream>>>(h, hf, srcI, dstI, W1, b1, W2, b2, W3, b3, out, E, ntiles);
        else
            mlp_edges<0><<<grid, 256, 0, stream>>>(h, hf, srcI, dstI, W1, b1, W2, b2, W3, b3, out, E, ntiles);
    }
}